// Round 11
// baseline (107.709 us; speedup 1.0000x reference)
//
#include <hip/hip_runtime.h>
#include <hip/hip_bf16.h>

#define N_ 32
#define C_ 128
#define H_ 56
#define W_ 56
#define K_ 256
#define HW_ (H_*W_)
#define HP_ 58    // padded spatial dim
#define STEPS 18  // 9 taps x 2 channel-halves (BK=64)

typedef __attribute__((ext_vector_type(8))) __bf16 bf16x8;
typedef __attribute__((ext_vector_type(8))) unsigned short ushort8;
typedef __attribute__((ext_vector_type(4))) float f32x4;

typedef __attribute__((address_space(1))) const unsigned int g1_u32;
typedef __attribute__((address_space(3))) unsigned int l3_u32;

__device__ __forceinline__ void dma16(const void* g, void* l) {
    __builtin_amdgcn_global_load_lds((g1_u32*)g, (l3_u32*)l, 16, 0, 0);
}

__device__ __forceinline__ unsigned short f2bf(float f) {
    unsigned int u = __builtin_bit_cast(unsigned int, f);
    u += 0x7FFFu + ((u >> 16) & 1u);   // round-to-nearest-even
    return (unsigned short)(u >> 16);
}

// ---------------- weight repack: OIHW fp32 -> fragment-major bf16 ----------
// wp4 element [(step*2+rh)*8192 + ((kk*8+mi8)*64 + lane)*8 + j]
//   step = tap*2+hf ; k_out = rh*128 + mi8*16 + (lane&15)
//   c = hf*64 + kk*32 + (lane>>4)*8 + j
// A-fragment load = one global_load_dwordx4 per lane, 1KB coalesced per wave.
__global__ void repack_w4_kernel(const float* __restrict__ w,
                                 unsigned short* __restrict__ wp4) {
    int o = blockIdx.x * 256 + threadIdx.x;
    if (o >= STEPS * 2 * 8192) return;
    int j    = o & 7;
    int lane = (o >> 3) & 63;
    int mi8  = (o >> 9) & 7;
    int kk   = (o >> 12) & 1;
    int rh   = (o >> 13) & 1;
    int hf   = (o >> 14) & 1;
    int tap  = o >> 15;
    int k = rh * 128 + mi8 * 16 + (lane & 15);
    int c = hf * 64 + kk * 32 + (lane >> 4) * 8 + j;
    wp4[o] = f2bf(w[(k * C_ + c) * 9 + tap]);
}

// ---------------- x prepack: NCHW fp32 -> padded NHWC bf16 -----------------
__global__ void pack_x_kernel(const float* __restrict__ x,
                              unsigned short* __restrict__ xp) {
    __shared__ unsigned short Lt[128 * 57];
    const int t  = threadIdx.x;               // 256
    const int b  = blockIdx.x;                // n*58 + hp
    const int n  = b / HP_;
    const int hp = b - n * HP_;
    unsigned short* orow = xp + ((size_t)(n * HP_ + hp) * HP_) * 128;

    ushort8 z = {0, 0, 0, 0, 0, 0, 0, 0};
    if (hp == 0 || hp == HP_ - 1) {
        for (int u = t; u < 928; u += 256)
            *(ushort8*)(orow + u * 8) = z;
        return;
    }
    const int h = hp - 1;
    const float* src = x + ((size_t)n * C_ * HW_ + h * W_);
    #pragma unroll
    for (int k = 0; k < 28; ++k) {
        int idx = k * 256 + t;
        int c = idx / 56, w2 = idx - 56 * c;
        Lt[c * 57 + w2] = f2bf(src[c * HW_ + w2]);
    }
    __syncthreads();
    for (int u = t; u < 928; u += 256) {
        int wp = u >> 4, c8 = u & 15;
        ushort8 v = z;
        if (wp >= 1 && wp <= 56) {
            #pragma unroll
            for (int j = 0; j < 8; ++j)
                v[j] = Lt[(c8 * 8 + j) * 57 + (wp - 1)];
        }
        *(ushort8*)(orow + u * 8) = v;
    }
}

// ---------------- main conv: A from L2 direct, B in 3-buffer LDS ring ------
// Block 256 kout x 128 px, 8 waves 4M x 2N, wave 64x64 (mi=4, ni=4), BK=64.
// Per step: 8 B ds_reads -> STAGE_B(k+2) (2 DMA) -> A-prefetch(k+1) (8 global)
// -> 32 MFMA -> vmcnt(10) [stage(k+2)+A(k+1) stay in flight] -> s_barrier.
// ONE barrier/step; no lgkmcnt asm (consumption ordering covers ring hazard).
__launch_bounds__(512, 1)
__global__ void conv_mfma10_kernel(const unsigned short* __restrict__ xp,
                                   const unsigned short* __restrict__ wp4,
                                   const float* __restrict__ bias,
                                   float* __restrict__ out) {
    __shared__ __align__(16) unsigned char Bl[3][16384];

    const int t    = threadIdx.x;
    const int lane = t & 63;
    const int wid  = t >> 6;
    const int wr   = wid >> 1;   // M wave 0..3 (64 kout each)
    const int wc   = wid & 1;    // N wave 0..1 (64 px each)
    const int lp   = lane & 15;
    const int lk   = lane >> 4;
    const int rh   = wr >> 1;
    const int m8b  = (wr & 1) * 4;

    // bijective XCD swizzle (784 % 8 == 0): 98 contiguous blocks per XCD
    const int b    = blockIdx.x;
    const int orig = (b & 7) * 98 + (b >> 3);
    const int pix0 = orig * 128;

    // ---- B staging sources (2 DMAs/thread; step adds (r*58+s)*128 + hf*64) ----
    const unsigned short* bsrc[2];
    #pragma unroll
    for (int i = 0; i < 2; ++i) {
        int u   = i * 512 + t;            // dest 16B-unit 0..1023
        int pxd = u >> 3;
        int sl  = (u & 7) ^ (pxd & 7);    // inverse-swizzled source slot
        int px  = pix0 + pxd;
        int n   = px / HW_;
        int pr  = px - n * HW_;
        int h   = pr / W_, w = pr - W_ * h;
        bsrc[i] = xp + (((size_t)(n * HP_) + h) * HP_ + w) * 128 + sl * 8;
    }

    // ---- B LDS read byte offsets (proven conflict-free XOR layout) ----
    int boff[2][4];
    #pragma unroll
    for (int kk = 0; kk < 2; ++kk)
        #pragma unroll
        for (int ni = 0; ni < 4; ++ni) {
            int pxl = wc * 64 + ni * 16 + lp;            // 0..127
            boff[kk][ni] = (pxl * 8 + ((kk * 4 + lk) ^ (pxl & 7))) * 16;
        }

    const ushort8* W8 = (const ushort8*)wp4;

    f32x4 acc[4][4];
    #pragma unroll
    for (int mi = 0; mi < 4; ++mi)
        #pragma unroll
        for (int ni = 0; ni < 4; ++ni)
            acc[mi][ni] = (f32x4){0.f, 0.f, 0.f, 0.f};

#define STAGE_B(S, BUF)                                                       \
    {                                                                         \
        const int tap_ = (S) >> 1, hf_ = (S) & 1;                             \
        const int xo_  = ((tap_ / 3) * HP_ + (tap_ % 3)) * 128 + hf_ * 64;    \
        dma16(bsrc[0] + xo_, Bl[BUF] + t * 16);                               \
        dma16(bsrc[1] + xo_, Bl[BUF] + (512 + t) * 16);                       \
    }

#define LOAD_A(S, DST)                                                        \
    _Pragma("unroll")                                                         \
    for (int kk = 0; kk < 2; ++kk)                                            \
        _Pragma("unroll")                                                     \
        for (int mi = 0; mi < 4; ++mi)                                        \
            DST[kk][mi] = __builtin_bit_cast(bf16x8,                          \
                W8[((S) * 2 + rh) * 1024 + (kk * 8 + m8b + mi) * 64 + lane]);

    bf16x8 aT[2][2][4];   // [step parity][kk][mi] — compile-time under unroll

    // prologue: B(0), B(1) staged; A(0) prefetched
    STAGE_B(0, 0)
    STAGE_B(1, 1)
    LOAD_A(0, aT[0])
    asm volatile("s_waitcnt vmcnt(10)" ::: "memory");   // B(0) landed
    __builtin_amdgcn_s_barrier();

    #pragma unroll
    for (int k = 0; k < STEPS; ++k) {
        const int cur = k % 3;
        const int pk  = k & 1;

        bf16x8 bb[2][4];
        #pragma unroll
        for (int kk = 0; kk < 2; ++kk)
            #pragma unroll
            for (int ni = 0; ni < 4; ++ni)
                bb[kk][ni] = __builtin_bit_cast(bf16x8,
                    *(const ushort8*)(Bl[cur] + boff[kk][ni]));

        if (k + 2 < STEPS) { STAGE_B(k + 2, (k + 2) % 3) }
        if (k + 1 < STEPS) { LOAD_A(k + 1, aT[pk ^ 1]) }

        __builtin_amdgcn_s_setprio(1);
        #pragma unroll
        for (int kk = 0; kk < 2; ++kk)
            #pragma unroll
            for (int ni = 0; ni < 4; ++ni)
                #pragma unroll
                for (int mi = 0; mi < 4; ++mi)
                    acc[mi][ni] = __builtin_amdgcn_mfma_f32_16x16x32_bf16(
                        aT[pk][kk][mi], bb[kk][ni], acc[mi][ni], 0, 0, 0);
        __builtin_amdgcn_s_setprio(0);

        if (k + 1 < STEPS) {
            if (k + 2 < STEPS) asm volatile("s_waitcnt vmcnt(10)" ::: "memory");
            else               asm volatile("s_waitcnt vmcnt(8)"  ::: "memory");
            __builtin_amdgcn_s_barrier();
        }
    }
#undef STAGE_B
#undef LOAD_A

    // ---- epilogue: bias + fp32 store ----
    #pragma unroll
    for (int ni = 0; ni < 4; ++ni) {
        int px = pix0 + wc * 64 + ni * 16 + lp;
        int n  = px / HW_;
        int pr = px - n * HW_;
        float* ob = out + (size_t)n * K_ * HW_ + pr;
        #pragma unroll
        for (int mi = 0; mi < 4; ++mi) {
            int kb = wr * 64 + mi * 16 + lk * 4;
            f32x4 bv = *(const f32x4*)(bias + kb);
            #pragma unroll
            for (int j = 0; j < 4; ++j)
                ob[(size_t)(kb + j) * HW_] = acc[mi][ni][j] + bv[j];
        }
    }
}

// ---------------- fallback (reg-staged fp32 path, no workspace xp) ---------
__launch_bounds__(256, 2)
__global__ void conv_mfma3_kernel(const float* __restrict__ x,
                                  const unsigned short* __restrict__ wp2,
                                  const float* __restrict__ bias,
                                  float* __restrict__ out) {
    __shared__ unsigned short Xt[2][232 * 40];
    const int t    = threadIdx.x;
    const int lane = t & 63;
    const int wid  = t >> 6;
    const int b    = blockIdx.x;
    const int orig = (b & 7) * 112 + (b >> 3);
    const int n    = orig / 28;
    const int rp   = orig - n * 28;
    const int h0   = rp * 2;
    const int lp = lane & 15;
    const int lk = lane >> 4;
    int bofs[7];
    #pragma unroll
    for (int ni = 0; ni < 7; ++ni) {
        int p  = ni * 16 + lp;
        int hr = (p >= 56) ? 1 : 0;
        int pw = p - hr * 56;
        bofs[ni] = (hr * 58 + pw) * 40 + lk * 8;
    }
    bool  ok[4], v928[4];
    const float* xq[4];
    int   ldsw[4];
    #pragma unroll
    for (int i = 0; i < 4; ++i) {
        int it = i * 256 + t;
        v928[i] = (it < 928);
        int itc  = v928[i] ? it : 0;
        int csub = (itc >= 232) + (itc >= 464) + (itc >= 696);
        int col  = itc - 232 * csub;
        int hh   = col / 58;
        int ww   = col - 58 * hh;
        int hin  = h0 + hh - 1;
        int win  = ww - 1;
        ok[i]   = v928[i] && (unsigned)hin < 56u && (unsigned)win < 56u;
        xq[i]   = x + (((n * C_ + csub * 8) * H_ + hin) * W_ + win);
        ldsw[i] = col * 40 + csub * 8;
    }
    float xv[4][8];
#define STAGE_LOAD(CH)                                                 \
    _Pragma("unroll")                                                  \
    for (int i = 0; i < 4; ++i)                                        \
        _Pragma("unroll")                                              \
        for (int j = 0; j < 8; ++j)                                    \
            xv[i][j] = ok[i] ? xq[i][((CH) * 32 + j) * HW_] : 0.f;
#define STAGE_WRITE(BUF)                                               \
    _Pragma("unroll")                                                  \
    for (int i = 0; i < 4; ++i)                                        \
        if (v928[i]) {                                                 \
            ushort8 v;                                                 \
            _Pragma("unroll")                                          \
            for (int j = 0; j < 8; ++j) v[j] = f2bf(xv[i][j]);         \
            *(ushort8*)(&Xt[BUF][ldsw[i]]) = v;                        \
        }
    f32x4 acc[4][7];
    #pragma unroll
    for (int mi = 0; mi < 4; ++mi)
        #pragma unroll
        for (int ni = 0; ni < 7; ++ni)
            acc[mi][ni] = (f32x4){0.f, 0.f, 0.f, 0.f};
    STAGE_LOAD(0)
    STAGE_WRITE(0)
    __syncthreads();
    const ushort8* W8 = (const ushort8*)wp2;
    for (int cc = 0; cc < 4; ++cc) {
        const int cur = cc & 1;
        if (cc < 3) { STAGE_LOAD(cc + 1) }
        const int tb = wid * 1024 + cc * 64 + lane;
        #pragma unroll
        for (int tap = 0; tap < 9; ++tap) {
            const int r    = tap / 3;
            const int s    = tap - 3 * r;
            const int toff = (r * 58 + s) * 40;
            bf16x8 a[4];
            #pragma unroll
            for (int mi = 0; mi < 4; ++mi)
                a[mi] = __builtin_bit_cast(bf16x8, W8[tap * 4096 + tb + mi * 256]);
            bf16x8 bfr[7];
            #pragma unroll
            for (int ni = 0; ni < 7; ++ni)
                bfr[ni] = __builtin_bit_cast(bf16x8,
                    *(const ushort8*)(&Xt[cur][bofs[ni] + toff]));
            #pragma unroll
            for (int ni = 0; ni < 7; ++ni)
                #pragma unroll
                for (int mi = 0; mi < 4; ++mi)
                    acc[mi][ni] = __builtin_amdgcn_mfma_f32_16x16x32_bf16(
                        a[mi], bfr[ni], acc[mi][ni], 0, 0, 0);
        }
        if (cc < 3) {
            STAGE_WRITE(cur ^ 1)
            __syncthreads();
        }
    }
    #pragma unroll
    for (int mi = 0; mi < 4; ++mi) {
        #pragma unroll
        for (int j = 0; j < 4; ++j) {
            int kout = wid * 64 + mi * 16 + lk * 4 + j;
            float bv = bias[kout];
            float* op = out + ((n * K_ + kout) * H_ + h0) * W_;
            #pragma unroll
            for (int ni = 0; ni < 7; ++ni) {
                int p  = ni * 16 + lp;
                int hr = (p >= 56) ? 1 : 0;
                int pw = p - hr * 56;
                op[hr * W_ + pw] = acc[mi][ni][j] + bv;
            }
        }
    }
#undef STAGE_LOAD
#undef STAGE_WRITE
}

// legacy repack for the fallback path
__global__ void repack_w2_kernel(const float* __restrict__ w,
                                 unsigned short* __restrict__ wp2) {
    int o = blockIdx.x * 256 + threadIdx.x;
    if (o >= 9 * 16 * 4 * 64 * 8) return;
    int j   = o & 7;
    int l   = (o >> 3) & 63;
    int cc  = (o >> 9) & 3;
    int kg  = (o >> 11) & 15;
    int tap = o >> 15;
    int k = kg * 16 + (l & 15);
    int c = cc * 32 + (l >> 4) * 8 + j;
    wp2[o] = f2bf(w[(k * C_ + c) * 9 + tap]);
}

__global__ void conv_naive_kernel(const float* __restrict__ x,
                                  const float* __restrict__ w,
                                  const float* __restrict__ b,
                                  float* __restrict__ out) {
    int idx = blockIdx.x * 256 + threadIdx.x;
    if (idx >= N_ * K_ * HW_) return;
    int pw = idx % 56; int tmp = idx / 56;
    int h  = tmp % 56; tmp /= 56;
    int k  = tmp % 256; int n = tmp / 256;
    float acc = b[k];
    for (int c = 0; c < C_; ++c)
        for (int r = 0; r < 3; ++r) {
            int hin = h + r - 1;
            if ((unsigned)hin >= 56u) continue;
            for (int s = 0; s < 3; ++s) {
                int win = pw + s - 1;
                if ((unsigned)win >= 56u) continue;
                acc += x[((n * C_ + c) * H_ + hin) * W_ + win] * w[(k * C_ + c) * 9 + r * 3 + s];
            }
        }
    out[idx] = acc;
}

extern "C" void kernel_launch(void* const* d_in, const int* in_sizes, int n_in,
                              void* d_out, int out_size, void* d_ws, size_t ws_size,
                              hipStream_t stream) {
    const float* x = (const float*)d_in[0];
    const float* w = (const float*)d_in[1];
    const float* b = (const float*)d_in[2];
    float* out = (float*)d_out;

    const size_t xp_bytes = (size_t)N_ * HP_ * HP_ * C_ * 2;              // 27,557,888
    const size_t wp_bytes = (size_t)STEPS * 2 * 8192 * 2;                 // 589,824

    if (ws_size >= xp_bytes + wp_bytes) {
        unsigned short* xpad = (unsigned short*)d_ws;
        unsigned short* wp4  = (unsigned short*)((char*)d_ws + xp_bytes);
        pack_x_kernel<<<N_ * HP_, 256, 0, stream>>>(x, xpad);
        repack_w4_kernel<<<(STEPS * 2 * 8192 + 255) / 256, 256, 0, stream>>>(w, wp4);
        conv_mfma10_kernel<<<784, 512, 0, stream>>>(xpad, wp4, b, out);
    } else if (ws_size >= wp_bytes) {
        unsigned short* wp2 = (unsigned short*)d_ws;
        repack_w2_kernel<<<(9 * 16 * 4 * 64 * 8 + 255) / 256, 256, 0, stream>>>(w, wp2);
        conv_mfma3_kernel<<<896, 256, 0, stream>>>(x, wp2, b, out);
    } else {
        conv_naive_kernel<<<(N_ * K_ * HW_ + 255) / 256, 256, 0, stream>>>(x, w, b, out);
    }
}

// Round 12
// 83.622 us; speedup vs baseline: 1.2880x; 1.2880x over previous
//
#include <hip/hip_runtime.h>
#include <hip/hip_bf16.h>

#define N_ 32
#define C_ 128
#define H_ 56
#define W_ 56
#define K_ 256
#define HW_ (H_*W_)
#define HP_ 58   // padded spatial dim
#define PL_ 234  // LDS plane stride in 16B units

typedef __attribute__((ext_vector_type(8))) __bf16 bf16x8;
typedef __attribute__((ext_vector_type(8))) unsigned short ushort8;
typedef __attribute__((ext_vector_type(4))) float f32x4;

typedef __attribute__((address_space(1))) const unsigned int g1_u32;
typedef __attribute__((address_space(3))) unsigned int l3_u32;

__device__ __forceinline__ void dma16(const void* g, void* l) {
    __builtin_amdgcn_global_load_lds((g1_u32*)g, (l3_u32*)l, 16, 0, 0);
}

__device__ __forceinline__ unsigned short f2bf(float f) {
    unsigned int u = __builtin_bit_cast(unsigned int, f);
    u += 0x7FFFu + ((u >> 16) & 1u);   // round-to-nearest-even
    return (unsigned short)(u >> 16);
}

// ---------------- weight repack: OIHW fp32 -> fragment-major bf16 ----------
// wp2[((tap*16 + kg)*4 + cc)*64 + lane][j]: k = kg*16+(lane&15), c = cc*32+(lane>>4)*8+j
__global__ void repack_w2_kernel(const float* __restrict__ w,
                                 unsigned short* __restrict__ wp2) {
    int o = blockIdx.x * 256 + threadIdx.x;
    if (o >= 9 * 16 * 4 * 64 * 8) return;
    int j   = o & 7;
    int l   = (o >> 3) & 63;
    int cc  = (o >> 9) & 3;
    int kg  = (o >> 11) & 15;
    int tap = o >> 15;
    int k = kg * 16 + (l & 15);
    int c = cc * 32 + (l >> 4) * 8 + j;
    wp2[o] = f2bf(w[(k * C_ + c) * 9 + tap]);
}

// ---------------- x prepack: NCHW fp32 -> padded NHWC bf16 -----------------
__global__ void pack_x_kernel(const float* __restrict__ x,
                              unsigned short* __restrict__ xp) {
    __shared__ unsigned short Lt[128 * 57];
    const int t  = threadIdx.x;               // 256
    const int b  = blockIdx.x;                // n*58 + hp
    const int n  = b / HP_;
    const int hp = b - n * HP_;
    unsigned short* orow = xp + ((size_t)(n * HP_ + hp) * HP_) * 128;

    ushort8 z = {0, 0, 0, 0, 0, 0, 0, 0};
    if (hp == 0 || hp == HP_ - 1) {
        for (int u = t; u < 928; u += 256)
            *(ushort8*)(orow + u * 8) = z;
        return;
    }
    const int h = hp - 1;
    const float* src = x + ((size_t)n * C_ * HW_ + h * W_);
    #pragma unroll
    for (int k = 0; k < 28; ++k) {
        int idx = k * 256 + t;
        int c = idx / 56, w2 = idx - 56 * c;
        Lt[c * 57 + w2] = f2bf(src[c * HW_ + w2]);
    }
    __syncthreads();
    for (int u = t; u < 928; u += 256) {
        int wp = u >> 4, c8 = u & 15;
        ushort8 v = z;
        if (wp >= 1 && wp <= 56) {
            #pragma unroll
            for (int j = 0; j < 8; ++j)
                v[j] = Lt[(c8 * 8 + j) * 57 + (wp - 1)];
        }
        *(ushort8*)(orow + u * 8) = v;
    }
}

// ---------------- main conv: R7 structure + A tap-ahead prefetch -----------
// Block: 256 kout x 112 px (2 rows), 4 waves, wave tile 64x112 (mi=4,ni=7).
// 3-buffer B ring w/ counted vmcnt (R7-proven). NEW: A fragments for global
// tap g+1 loaded into parity regs before tap g's MFMA cluster -> the 9
// per-chunk L2 latency chains are hidden under MFMAs; prefetch crosses
// barriers (vmcnt(8) = 4 x-DMA + 4 A-loads in flight).
__launch_bounds__(256, 2)
__global__ void conv_mfma11_kernel(const unsigned short* __restrict__ xp,
                                   const unsigned short* __restrict__ wp2,
                                   const float* __restrict__ bias,
                                   float* __restrict__ out) {
    __shared__ __align__(16) unsigned char Xt[3][16384];

    const int t    = threadIdx.x;
    const int lane = t & 63;
    const int wid  = t >> 6;

    // bijective XCD swizzle (896 % 8 == 0)
    const int b    = blockIdx.x;
    const int orig = (b & 7) * 112 + (b >> 3);
    const int n    = orig / 28;
    const int rp   = orig - n * 28;
    const int h0   = rp * 2;

    const int lp = lane & 15;
    const int lk = lane >> 4;

    // B-fragment byte offsets (tap adds (r*58+s)*16)
    int bunit[7];
    #pragma unroll
    for (int ni = 0; ni < 7; ++ni) {
        int p  = ni * 16 + lp;
        int hr = (p >= 56) ? 1 : 0;
        int pw = p - hr * 56;
        bunit[ni] = (lk * PL_ + hr * HP_ + pw) * 16;
    }

    // staging geometry: slot u = i*256+t -> (csub,col) = (u/PL_, u%PL_);
    // invalid slots clamp source to xp base (garbage lands in pad units).
    const unsigned short* gsrc[4];
    #pragma unroll
    for (int i = 0; i < 4; ++i) {
        int u    = i * 256 + t;
        int csub = u / PL_;
        int col  = u - PL_ * csub;
        bool ok  = (csub < 4) && (col < 232);
        int csc  = ok ? csub : 0;
        int colc = ok ? col : 0;
        int hh   = colc / HP_;
        int ww   = colc - HP_ * hh;
        gsrc[i]  = ok ? xp + (((size_t)(n * HP_ + h0 + hh) * HP_ + ww) * 128 + csc * 8)
                      : xp;
    }

    f32x4 acc[4][7];
    #pragma unroll
    for (int mi = 0; mi < 4; ++mi)
        #pragma unroll
        for (int ni = 0; ni < 7; ++ni)
            acc[mi][ni] = (f32x4){0.f, 0.f, 0.f, 0.f};

    const ushort8* W8 = (const ushort8*)wp2;
    bf16x8 areg[2][4];   // parity-indexed A double-buffer (compile-time idx)

#define STAGE(CH, BUF)                                                     \
    _Pragma("unroll")                                                      \
    for (int i = 0; i < 4; ++i)                                            \
        dma16(gsrc[i] + (CH) * 32, Xt[BUF] + i * 4096 + wid * 1024);

#define LOAD_A(TAP, CC, PAR)                                               \
    _Pragma("unroll")                                                      \
    for (int mi = 0; mi < 4; ++mi)                                         \
        areg[PAR][mi] = __builtin_bit_cast(bf16x8,                         \
            W8[(TAP) * 4096 + (wid * 16 + (CC)) * 64 + lane + mi * 256]);

    // prologue: A(tap0,cc0) first (earliest L2 issue), then DMA chunks 0,1
    LOAD_A(0, 0, 0)
    STAGE(0, 0)
    STAGE(1, 1)
    asm volatile("s_waitcnt vmcnt(4)" ::: "memory");   // A(0)+buf0 landed
    __builtin_amdgcn_s_barrier();

    #pragma unroll
    for (int cc = 0; cc < 4; ++cc) {
        const int cur = cc % 3;

        #pragma unroll
        for (int tap = 0; tap < 9; ++tap) {
            const int g = cc * 9 + tap;     // global tap index (compile-time)
            const int p = g & 1;

            const int r    = tap / 3;
            const int s    = tap - 3 * r;
            const int toff = (r * HP_ + s) * 16;

            bf16x8 bfr[7];
            #pragma unroll
            for (int ni = 0; ni < 7; ++ni)
                bfr[ni] = __builtin_bit_cast(bf16x8,
                    *(const ushort8*)(Xt[cur] + bunit[ni] + toff));

            // prefetch A for global tap g+1 (crosses chunk boundary freely)
            if (g + 1 < 36) {
                const int nc = (g + 1) / 9;
                const int nt = (g + 1) - nc * 9;
                LOAD_A(nt, nc, p ^ 1)
            }

            __builtin_amdgcn_s_setprio(1);
            #pragma unroll
            for (int ni = 0; ni < 7; ++ni)
                #pragma unroll
                for (int mi = 0; mi < 4; ++mi)
                    acc[mi][ni] = __builtin_amdgcn_mfma_f32_16x16x32_bf16(
                        areg[p][mi], bfr[ni], acc[mi][ni], 0, 0, 0);
            __builtin_amdgcn_s_setprio(0);
        }

        if (cc < 2) { STAGE(cc + 2, (cc + 2) % 3) }    // newest vmem ops

        if (cc < 3) {
            // keep stage(cc+2) [if any] + A-prefetch(4) in flight
            if (cc < 2) asm volatile("s_waitcnt vmcnt(8)" ::: "memory");
            else        asm volatile("s_waitcnt vmcnt(4)" ::: "memory");
            __builtin_amdgcn_s_barrier();
        }
    }
#undef STAGE
#undef LOAD_A

    // epilogue: bias + fp32 store
    #pragma unroll
    for (int mi = 0; mi < 4; ++mi) {
        #pragma unroll
        for (int j = 0; j < 4; ++j) {
            int kout = wid * 64 + mi * 16 + lk * 4 + j;
            float bv = bias[kout];
            float* op = out + ((n * K_ + kout) * H_ + h0) * W_;
            #pragma unroll
            for (int ni = 0; ni < 7; ++ni) {
                int p  = ni * 16 + lp;
                int hr = (p >= 56) ? 1 : 0;
                int pw = p - hr * 56;
                op[hr * W_ + pw] = acc[mi][ni][j] + bv;
            }
        }
    }
}

// ---------------- fallback (reg-staged fp32 path, no workspace xp) ---------
__launch_bounds__(256, 2)
__global__ void conv_mfma3_kernel(const float* __restrict__ x,
                                  const unsigned short* __restrict__ wp2,
                                  const float* __restrict__ bias,
                                  float* __restrict__ out) {
    __shared__ unsigned short Xt[2][232 * 40];
    const int t    = threadIdx.x;
    const int lane = t & 63;
    const int wid  = t >> 6;
    const int b    = blockIdx.x;
    const int orig = (b & 7) * 112 + (b >> 3);
    const int n    = orig / 28;
    const int rp   = orig - n * 28;
    const int h0   = rp * 2;
    const int lp = lane & 15;
    const int lk = lane >> 4;
    int bofs[7];
    #pragma unroll
    for (int ni = 0; ni < 7; ++ni) {
        int p  = ni * 16 + lp;
        int hr = (p >= 56) ? 1 : 0;
        int pw = p - hr * 56;
        bofs[ni] = (hr * 58 + pw) * 40 + lk * 8;
    }
    bool  ok[4], v928[4];
    const float* xq[4];
    int   ldsw[4];
    #pragma unroll
    for (int i = 0; i < 4; ++i) {
        int it = i * 256 + t;
        v928[i] = (it < 928);
        int itc  = v928[i] ? it : 0;
        int csub = (itc >= 232) + (itc >= 464) + (itc >= 696);
        int col  = itc - 232 * csub;
        int hh   = col / 58;
        int ww   = col - 58 * hh;
        int hin  = h0 + hh - 1;
        int win  = ww - 1;
        ok[i]   = v928[i] && (unsigned)hin < 56u && (unsigned)win < 56u;
        xq[i]   = x + (((n * C_ + csub * 8) * H_ + hin) * W_ + win);
        ldsw[i] = col * 40 + csub * 8;
    }
    float xv[4][8];
#define STAGE_LOAD(CH)                                                 \
    _Pragma("unroll")                                                  \
    for (int i = 0; i < 4; ++i)                                        \
        _Pragma("unroll")                                              \
        for (int j = 0; j < 8; ++j)                                    \
            xv[i][j] = ok[i] ? xq[i][((CH) * 32 + j) * HW_] : 0.f;
#define STAGE_WRITE(BUF)                                               \
    _Pragma("unroll")                                                  \
    for (int i = 0; i < 4; ++i)                                        \
        if (v928[i]) {                                                 \
            ushort8 v;                                                 \
            _Pragma("unroll")                                          \
            for (int j = 0; j < 8; ++j) v[j] = f2bf(xv[i][j]);         \
            *(ushort8*)(&Xt[BUF][ldsw[i]]) = v;                        \
        }
    f32x4 acc[4][7];
    #pragma unroll
    for (int mi = 0; mi < 4; ++mi)
        #pragma unroll
        for (int ni = 0; ni < 7; ++ni)
            acc[mi][ni] = (f32x4){0.f, 0.f, 0.f, 0.f};
    STAGE_LOAD(0)
    STAGE_WRITE(0)
    __syncthreads();
    const ushort8* W8 = (const ushort8*)wp2;
    for (int cc = 0; cc < 4; ++cc) {
        const int cur = cc & 1;
        if (cc < 3) { STAGE_LOAD(cc + 1) }
        const int tb = wid * 1024 + cc * 64 + lane;
        #pragma unroll
        for (int tap = 0; tap < 9; ++tap) {
            const int r    = tap / 3;
            const int s    = tap - 3 * r;
            const int toff = (r * 58 + s) * 40;
            bf16x8 a[4];
            #pragma unroll
            for (int mi = 0; mi < 4; ++mi)
                a[mi] = __builtin_bit_cast(bf16x8, W8[tap * 4096 + tb + mi * 256]);
            bf16x8 bfr[7];
            #pragma unroll
            for (int ni = 0; ni < 7; ++ni)
                bfr[ni] = __builtin_bit_cast(bf16x8,
                    *(const ushort8*)(&Xt[cur][bofs[ni] + toff]));
            #pragma unroll
            for (int ni = 0; ni < 7; ++ni)
                #pragma unroll
                for (int mi = 0; mi < 4; ++mi)
                    acc[mi][ni] = __builtin_amdgcn_mfma_f32_16x16x32_bf16(
                        a[mi], bfr[ni], acc[mi][ni], 0, 0, 0);
        }
        if (cc < 3) {
            STAGE_WRITE(cur ^ 1)
            __syncthreads();
        }
    }
    #pragma unroll
    for (int mi = 0; mi < 4; ++mi) {
        #pragma unroll
        for (int j = 0; j < 4; ++j) {
            int kout = wid * 64 + mi * 16 + lk * 4 + j;
            float bv = bias[kout];
            float* op = out + ((n * K_ + kout) * H_ + h0) * W_;
            #pragma unroll
            for (int ni = 0; ni < 7; ++ni) {
                int p  = ni * 16 + lp;
                int hr = (p >= 56) ? 1 : 0;
                int pw = p - hr * 56;
                op[hr * W_ + pw] = acc[mi][ni][j] + bv;
            }
        }
    }
#undef STAGE_LOAD
#undef STAGE_WRITE
}

__global__ void conv_naive_kernel(const float* __restrict__ x,
                                  const float* __restrict__ w,
                                  const float* __restrict__ b,
                                  float* __restrict__ out) {
    int idx = blockIdx.x * 256 + threadIdx.x;
    if (idx >= N_ * K_ * HW_) return;
    int pw = idx % 56; int tmp = idx / 56;
    int h  = tmp % 56; tmp /= 56;
    int k  = tmp % 256; int n = tmp / 256;
    float acc = b[k];
    for (int c = 0; c < C_; ++c)
        for (int r = 0; r < 3; ++r) {
            int hin = h + r - 1;
            if ((unsigned)hin >= 56u) continue;
            for (int s = 0; s < 3; ++s) {
                int win = pw + s - 1;
                if ((unsigned)win >= 56u) continue;
                acc += x[((n * C_ + c) * H_ + hin) * W_ + win] * w[(k * C_ + c) * 9 + r * 3 + s];
            }
        }
    out[idx] = acc;
}

extern "C" void kernel_launch(void* const* d_in, const int* in_sizes, int n_in,
                              void* d_out, int out_size, void* d_ws, size_t ws_size,
                              hipStream_t stream) {
    const float* x = (const float*)d_in[0];
    const float* w = (const float*)d_in[1];
    const float* b = (const float*)d_in[2];
    float* out = (float*)d_out;

    const size_t xp_bytes = (size_t)N_ * HP_ * HP_ * C_ * 2;              // 27,557,888
    const size_t wp_bytes = (size_t)9 * 16 * 4 * 64 * 8 * 2;              // 589,824

    if (ws_size >= xp_bytes + wp_bytes) {
        unsigned short* xpad = (unsigned short*)d_ws;
        unsigned short* wp2  = (unsigned short*)((char*)d_ws + xp_bytes);
        pack_x_kernel<<<N_ * HP_, 256, 0, stream>>>(x, xpad);
        repack_w2_kernel<<<(9 * 16 * 4 * 64 * 8 + 255) / 256, 256, 0, stream>>>(w, wp2);
        conv_mfma11_kernel<<<896, 256, 0, stream>>>(xpad, wp2, b, out);
    } else if (ws_size >= wp_bytes) {
        unsigned short* wp2 = (unsigned short*)d_ws;
        repack_w2_kernel<<<(9 * 16 * 4 * 64 * 8 + 255) / 256, 256, 0, stream>>>(w, wp2);
        conv_mfma3_kernel<<<896, 256, 0, stream>>>(x, wp2, b, out);
    } else {
        conv_naive_kernel<<<(N_ * K_ * HW_ + 255) / 256, 256, 0, stream>>>(x, w, b, out);
    }
}